// Round 1
// baseline (570.154 us; speedup 1.0000x reference)
//
#include <hip/hip_runtime.h>

// deformMP: B=4, Cc=256, ci=64, H=W=128, GN groups=32, eps=1e-5
// ws layout (floats): xd[4.19M] offs[1.18M] osum[4.19M] t3[16.78M] mrs1[256] mrs2[256]
//                     w1T[16K] w3T[16K] wdT[36.9K]  => 105,662,464 bytes total

#define HW 16384
#define WIDTH 128

// ---- K0: transpose weights so inner-loop weight reads are wave-uniform (s_load) ----
__global__ __launch_bounds__(256) void k_prep(const float* __restrict__ w1, const float* __restrict__ w3,
                                              const float* __restrict__ wdef,
                                              float* __restrict__ w1T, float* __restrict__ w3T,
                                              float* __restrict__ wdT) {
  int i = blockIdx.x * 256 + threadIdx.x;
  if (i < 16384) { int o = i >> 8, c = i & 255; w1T[c * 64 + o] = w1[i]; }    // w1 [64][256] -> [c][o]
  if (i < 16384) { int o = i >> 6, c = i & 63;  w3T[c * 256 + o] = w3[i]; }   // w3 [256][64] -> [c][o]
  if (i < 36864) {                                                            // w_def [64][64][3][3] -> [k][c][o]
    int o = i / 576, r = i - o * 576;
    int c = r / 9, k = r - c * 9;
    wdT[(k * 64 + c) * 64 + o] = wdef[i];
  }
}

// ---- K1: conv1x1 256->64. Block=256 thr (4 waves): wave w -> 16 outputs, lane -> 4 pixels ----
__global__ __launch_bounds__(256) void k_conv1(const float* __restrict__ x, const float* __restrict__ w1T,
                                               float* __restrict__ y) {
  int tid = threadIdx.x;
  int lane = tid & 63;
  int o0 = __builtin_amdgcn_readfirstlane(tid >> 6) * 16;
  int b = blockIdx.x >> 6;
  int hw = ((blockIdx.x & 63) << 8) + (lane << 2);
  const float* xb = x + (size_t)b * 256 * HW + hw;
  float acc[16][4];
#pragma unroll
  for (int i = 0; i < 16; i++)
#pragma unroll
    for (int j = 0; j < 4; j++) acc[i][j] = 0.f;
  for (int c = 0; c < 256; c++) {
    float4 xv = *(const float4*)(xb + (size_t)c * HW);
    const float* wp = w1T + c * 64 + o0;  // wave-uniform -> s_load
#pragma unroll
    for (int i = 0; i < 16; i++) {
      float w = wp[i];
      acc[i][0] += xv.x * w; acc[i][1] += xv.y * w;
      acc[i][2] += xv.z * w; acc[i][3] += xv.w * w;
    }
  }
  float* yb = y + (size_t)b * 64 * HW + hw;
#pragma unroll
  for (int i = 0; i < 16; i++)
    *(float4*)(yb + (size_t)(o0 + i) * HW) = make_float4(acc[i][0], acc[i][1], acc[i][2], acc[i][3]);
}

// ---- K2: GN stats, one block per (b,group); channels in a group are contiguous ----
template <int CPG>
__global__ __launch_bounds__(256) void k_gnstats(const float* __restrict__ y, float* __restrict__ mrs) {
  int bg = blockIdx.x;  // b*32+g
  const float* p = y + (size_t)bg * CPG * HW;
  float s = 0.f, ss = 0.f;
  for (int i = threadIdx.x; i < CPG * HW; i += 256) { float v = p[i]; s += v; ss += v * v; }
#pragma unroll
  for (int off = 32; off; off >>= 1) { s += __shfl_down(s, off); ss += __shfl_down(ss, off); }
  __shared__ float ls[4], lss[4];
  int wv = threadIdx.x >> 6;
  if ((threadIdx.x & 63) == 0) { ls[wv] = s; lss[wv] = ss; }
  __syncthreads();
  if (threadIdx.x == 0) {
    float S = ls[0] + ls[1] + ls[2] + ls[3];
    float SS = lss[0] + lss[1] + lss[2] + lss[3];
    const float n = (float)(CPG * HW);
    float mu = S / n;
    float var = SS / n - mu * mu;
    mrs[bg] = mu;
    mrs[128 + bg] = rsqrtf(var + 1e-5f);
  }
}

// ---- K3: apply GN1 + ReLU in place on xd ----
__global__ __launch_bounds__(256) void k_gnapply1(float* __restrict__ xd, const float* __restrict__ mrs,
                                                  const float* __restrict__ g1, const float* __restrict__ b1) {
  int i4 = blockIdx.x * 256 + threadIdx.x;  // float4 index, 2^20 total
  int b = i4 >> 18;                          // 64*16384/4 = 2^18 per batch
  int c = (i4 >> 12) & 63;                   // 4096 float4 per channel
  int g = c >> 1;
  float mu = mrs[b * 32 + g], rs = mrs[128 + b * 32 + g];
  float ga = g1[c] * rs, be = b1[c] - mu * ga;
  float4 v = ((const float4*)xd)[i4];
  v.x = fmaxf(v.x * ga + be, 0.f);
  v.y = fmaxf(v.y * ga + be, 0.f);
  v.z = fmaxf(v.z * ga + be, 0.f);
  v.w = fmaxf(v.w * ga + be, 0.f);
  ((float4*)xd)[i4] = v;
}

// ---- K4: conv3x3 64->18 (offsets), pad 1. Block = 2 rows x 128 cols ----
__global__ __launch_bounds__(256) void k_off(const float* __restrict__ xd, const float* __restrict__ woff,
                                             float* __restrict__ offs) {
  int tid = threadIdx.x;
  int b = blockIdx.x >> 6;
  int r0 = (blockIdx.x & 63) << 1;
  int y = r0 + (tid >> 7);
  int xc = tid & 127;
  const float* xb = xd + (size_t)b * 64 * HW;
  float acc[18];
#pragma unroll
  for (int o = 0; o < 18; o++) acc[o] = 0.f;
  for (int c = 0; c < 64; c++) {
    const float* pc = xb + (size_t)c * HW;
    float v[3][3];
#pragma unroll
    for (int ky = 0; ky < 3; ky++) {
      int yy = y + ky - 1;
      bool vy = (unsigned)yy < 128u;
#pragma unroll
      for (int kx = 0; kx < 3; kx++) {
        int xx = xc + kx - 1;
        bool vx = (unsigned)xx < 128u;
        v[ky][kx] = (vy && vx) ? pc[yy * WIDTH + xx] : 0.f;
      }
    }
    const float* wc = woff + c * 9;  // w_off [18][64][3][3]
#pragma unroll
    for (int o = 0; o < 18; o++) {
      const float* wo = wc + o * 576;  // uniform -> s_load
#pragma unroll
      for (int k = 0; k < 9; k++) acc[o] += v[k / 3][k % 3] * wo[k];
    }
  }
  float* op = offs + (size_t)b * 18 * HW + y * WIDTH + xc;
#pragma unroll
  for (int o = 0; o < 18; o++) op[(size_t)o * HW] = acc[o];
}

// ---- K5: deform conv v1 + residual (osum = deform(xd, offs, w_def) + xd) ----
__global__ __launch_bounds__(256) void k_deform(const float* __restrict__ xd, const float* __restrict__ offs,
                                                const float* __restrict__ wdT, float* __restrict__ osum) {
  int tid = threadIdx.x;
  int b = blockIdx.x >> 6;
  int pix = ((blockIdx.x & 63) << 8) + tid;
  int y = pix >> 7, xc = pix & 127;
  const float* ob = offs + (size_t)b * 18 * HW + pix;
  const float* xb = xd + (size_t)b * 64 * HW;
  float acc[64];
#pragma unroll
  for (int o = 0; o < 64; o++) acc[o] = 0.f;
#pragma unroll 1
  for (int k = 0; k < 9; k++) {
    float dy = ob[(size_t)(2 * k) * HW];
    float dx = ob[(size_t)(2 * k + 1) * HW];
    float py = (float)(y + k / 3 - 1) + dy;
    float px = (float)(xc + k % 3 - 1) + dx;
    float y0f = floorf(py), x0f = floorf(px);
    float ay = py - y0f, ax = px - x0f;
    int y0 = (int)y0f, x0 = (int)x0f;
    int y1i = y0 + 1, x1i = x0 + 1;
    float by0 = 1.f - ay, bx0 = 1.f - ax;
    bool vy0 = (unsigned)y0 < 128u, vy1 = (unsigned)y1i < 128u;
    bool vx0 = (unsigned)x0 < 128u, vx1 = (unsigned)x1i < 128u;
    float w00 = (vy0 && vx0) ? by0 * bx0 : 0.f;
    float w01 = (vy0 && vx1) ? by0 * ax : 0.f;
    float w10 = (vy1 && vx0) ? ay * bx0 : 0.f;
    float w11 = (vy1 && vx1) ? ay * ax : 0.f;
    int iy0 = min(max(y0, 0), 127), iy1 = min(max(y1i, 0), 127);
    int ix0 = min(max(x0, 0), 127), ix1 = min(max(x1i, 0), 127);
    int a00 = iy0 * WIDTH + ix0, a01 = iy0 * WIDTH + ix1;
    int a10 = iy1 * WIDTH + ix0, a11 = iy1 * WIDTH + ix1;
#pragma unroll 1
    for (int c = 0; c < 64; c++) {
      const float* pc = xb + (size_t)c * HW;
      float s = w00 * pc[a00] + w01 * pc[a01] + w10 * pc[a10] + w11 * pc[a11];
      const float* wp = wdT + (size_t)(k * 64 + c) * 64;  // uniform -> s_load
#pragma unroll
      for (int o = 0; o < 64; o++) acc[o] += s * wp[o];
    }
  }
  float* op = osum + (size_t)b * 64 * HW + pix;
  const float* xp = xb + pix;
#pragma unroll
  for (int o = 0; o < 64; o++) op[(size_t)o * HW] = acc[o] + xp[(size_t)o * HW];
}

// ---- K6: conv1x1 64->256 into t3; grid.y = 4 output-channel chunks of 64 ----
__global__ __launch_bounds__(256) void k_conv2(const float* __restrict__ osum, const float* __restrict__ w3T,
                                               float* __restrict__ t3) {
  int tid = threadIdx.x;
  int lane = tid & 63;
  int o0 = (blockIdx.y << 6) + __builtin_amdgcn_readfirstlane(tid >> 6) * 16;
  int b = blockIdx.x >> 6;
  int hw = ((blockIdx.x & 63) << 8) + (lane << 2);
  const float* ib = osum + (size_t)b * 64 * HW + hw;
  float acc[16][4];
#pragma unroll
  for (int i = 0; i < 16; i++)
#pragma unroll
    for (int j = 0; j < 4; j++) acc[i][j] = 0.f;
  for (int c = 0; c < 64; c++) {
    float4 xv = *(const float4*)(ib + (size_t)c * HW);
    const float* wp = w3T + c * 256 + o0;  // wave-uniform -> s_load
#pragma unroll
    for (int i = 0; i < 16; i++) {
      float w = wp[i];
      acc[i][0] += xv.x * w; acc[i][1] += xv.y * w;
      acc[i][2] += xv.z * w; acc[i][3] += xv.w * w;
    }
  }
  float* tb = t3 + (size_t)b * 256 * HW + hw;
#pragma unroll
  for (int i = 0; i < 16; i++)
    *(float4*)(tb + (size_t)(o0 + i) * HW) = make_float4(acc[i][0], acc[i][1], acc[i][2], acc[i][3]);
}

// ---- K8: out = relu(gn2(t3)) + x ----
__global__ __launch_bounds__(256) void k_final(const float* __restrict__ t3, const float* __restrict__ x,
                                               const float* __restrict__ mrs, const float* __restrict__ g3,
                                               const float* __restrict__ b3, float* __restrict__ out) {
  int i4 = blockIdx.x * 256 + threadIdx.x;  // float4 index, 2^22 total
  int b = i4 >> 20;                          // 256*16384/4 = 2^20 per batch
  int c = (i4 >> 12) & 255;
  int g = c >> 3;
  float mu = mrs[b * 32 + g], rs = mrs[128 + b * 32 + g];
  float ga = g3[c] * rs, be = b3[c] - mu * ga;
  float4 t = ((const float4*)t3)[i4];
  float4 xv = ((const float4*)x)[i4];
  float4 r;
  r.x = fmaxf(t.x * ga + be, 0.f) + xv.x;
  r.y = fmaxf(t.y * ga + be, 0.f) + xv.y;
  r.z = fmaxf(t.z * ga + be, 0.f) + xv.z;
  r.w = fmaxf(t.w * ga + be, 0.f) + xv.w;
  ((float4*)out)[i4] = r;
}

extern "C" void kernel_launch(void* const* d_in, const int* in_sizes, int n_in,
                              void* d_out, int out_size, void* d_ws, size_t ws_size,
                              hipStream_t stream) {
  const float* x    = (const float*)d_in[0];
  const float* w1   = (const float*)d_in[1];
  const float* g1   = (const float*)d_in[2];
  const float* b1   = (const float*)d_in[3];
  const float* woff = (const float*)d_in[4];
  const float* wdef = (const float*)d_in[5];
  const float* w3   = (const float*)d_in[6];
  const float* g3   = (const float*)d_in[7];
  const float* b3   = (const float*)d_in[8];
  float* ws = (float*)d_ws;

  float* xd   = ws;                 // 4,194,304
  float* offs = xd + 4194304;       // 1,179,648
  float* osum = offs + 1179648;     // 4,194,304
  float* t3   = osum + 4194304;     // 16,777,216
  float* mrs1 = t3 + 16777216;      // 256
  float* mrs2 = mrs1 + 256;         // 256
  float* w1T  = mrs2 + 256;         // 16,384
  float* w3T  = w1T + 16384;        // 16,384
  float* wdT  = w3T + 16384;        // 36,864
  float* out  = (float*)d_out;

  hipLaunchKernelGGL(k_prep, dim3(144), dim3(256), 0, stream, w1, w3, wdef, w1T, w3T, wdT);
  hipLaunchKernelGGL(k_conv1, dim3(256), dim3(256), 0, stream, x, w1T, xd);
  hipLaunchKernelGGL(k_gnstats<2>, dim3(128), dim3(256), 0, stream, xd, mrs1);
  hipLaunchKernelGGL(k_gnapply1, dim3(4096), dim3(256), 0, stream, xd, mrs1, g1, b1);
  hipLaunchKernelGGL(k_off, dim3(256), dim3(256), 0, stream, xd, woff, offs);
  hipLaunchKernelGGL(k_deform, dim3(256), dim3(256), 0, stream, xd, offs, wdT, osum);
  hipLaunchKernelGGL(k_conv2, dim3(256, 4), dim3(256), 0, stream, osum, w3T, t3);
  hipLaunchKernelGGL(k_gnstats<8>, dim3(128), dim3(256), 0, stream, t3, mrs2);
  hipLaunchKernelGGL(k_final, dim3(16384), dim3(256), 0, stream, t3, x, mrs2, g3, b3, out);
}

// Round 2
// 341.819 us; speedup vs baseline: 1.6680x; 1.6680x over previous
//
#include <hip/hip_runtime.h>

// deformMP: B=4, Cc=256, ci=64, H=W=128, GN groups=32, eps=1e-5
// ws layout (floats): xd[4.19M] offs[1.18M] osum[4.19M] t3[16.78M] mrs1[256] mrs2[256]
//                     w1T[16K] w3T[16K] wdT[36.9K] ps[2048]
// deform partials (3 x 4.19M) alias into t3's space (dead until conv2).

#define HW 16384
#define WIDTH 128

// ---- K0: transpose weights so inner-loop weight reads are wave-uniform (s_load) ----
__global__ __launch_bounds__(256) void k_prep(const float* __restrict__ w1, const float* __restrict__ w3,
                                              const float* __restrict__ wdef,
                                              float* __restrict__ w1T, float* __restrict__ w3T,
                                              float* __restrict__ wdT) {
  int i = blockIdx.x * 256 + threadIdx.x;
  if (i < 16384) { int o = i >> 8, c = i & 255; w1T[c * 64 + o] = w1[i]; }    // w1 [64][256] -> [c][o]
  if (i < 16384) { int o = i >> 6, c = i & 63;  w3T[c * 256 + o] = w3[i]; }   // w3 [256][64] -> [c][o]
  if (i < 36864) {                                                            // w_def [64][64][3][3] -> [k][c][o]
    int o = i / 576, r = i - o * 576;
    int c = r / 9, k = r - c * 9;
    wdT[(k * 64 + c) * 64 + o] = wdef[i];
  }
}

// ---- K1: conv1x1 256->64. Block=512 thr (8 waves): wave w -> 8 outputs, lane -> 1 float4 ----
// All 8 waves read the same 256-float x chunk -> L1 hits; x read once from HBM.
__global__ __launch_bounds__(512) void k_conv1(const float* __restrict__ x, const float* __restrict__ w1T,
                                               float* __restrict__ y) {
  int tid = threadIdx.x;
  int lane = tid & 63;
  int o0 = __builtin_amdgcn_readfirstlane(tid >> 6) * 8;  // 8 waves x 8 outs = 64
  int b = blockIdx.x >> 6;
  int hw = ((blockIdx.x & 63) << 8) + (lane << 2);
  const float* xb = x + (size_t)b * 256 * HW + hw;
  float acc[8][4];
#pragma unroll
  for (int i = 0; i < 8; i++)
#pragma unroll
    for (int j = 0; j < 4; j++) acc[i][j] = 0.f;
  for (int c = 0; c < 256; c++) {
    float4 xv = *(const float4*)(xb + (size_t)c * HW);
    const float* wp = w1T + c * 64 + o0;  // wave-uniform -> s_load
#pragma unroll
    for (int i = 0; i < 8; i++) {
      float w = wp[i];
      acc[i][0] += xv.x * w; acc[i][1] += xv.y * w;
      acc[i][2] += xv.z * w; acc[i][3] += xv.w * w;
    }
  }
  float* yb = y + (size_t)b * 64 * HW + hw;
#pragma unroll
  for (int i = 0; i < 8; i++)
    *(float4*)(yb + (size_t)(o0 + i) * HW) = make_float4(acc[i][0], acc[i][1], acc[i][2], acc[i][3]);
}

// ---- K2a: GN stats partials. grid (128, S); block reduces its slice -> ps[(bg*S+s)*2] ----
template <int CPG, int S>
__global__ __launch_bounds__(256) void k_gnstats_part(const float* __restrict__ y, float* __restrict__ ps) {
  int bg = blockIdx.x, sl = blockIdx.y;
  const int N4 = CPG * HW / 4 / S;
  const float4* p = (const float4*)(y + (size_t)bg * CPG * HW) + (size_t)sl * N4;
  float s = 0.f, ss = 0.f;
  for (int i = threadIdx.x; i < N4; i += 256) {
    float4 v = p[i];
    s += v.x + v.y + v.z + v.w;
    ss += v.x * v.x + v.y * v.y + v.z * v.z + v.w * v.w;
  }
#pragma unroll
  for (int off = 32; off; off >>= 1) { s += __shfl_down(s, off); ss += __shfl_down(ss, off); }
  __shared__ float ls[4], lss[4];
  int wv = threadIdx.x >> 6;
  if ((threadIdx.x & 63) == 0) { ls[wv] = s; lss[wv] = ss; }
  __syncthreads();
  if (threadIdx.x == 0) {
    ps[(bg * S + sl) * 2] = ls[0] + ls[1] + ls[2] + ls[3];
    ps[(bg * S + sl) * 2 + 1] = lss[0] + lss[1] + lss[2] + lss[3];
  }
}

// ---- K2b: finalize stats. 1 block, 128 threads (one per bg) ----
__global__ __launch_bounds__(128) void k_gnfin(const float* __restrict__ ps, float* __restrict__ mrs,
                                               int S, float n) {
  int bg = threadIdx.x;
  float s = 0.f, ss = 0.f;
  for (int sl = 0; sl < S; sl++) { s += ps[(bg * S + sl) * 2]; ss += ps[(bg * S + sl) * 2 + 1]; }
  float mu = s / n;
  float var = ss / n - mu * mu;
  mrs[bg] = mu;
  mrs[128 + bg] = rsqrtf(var + 1e-5f);
}

// ---- K3: apply GN1 + ReLU in place on xd ----
__global__ __launch_bounds__(256) void k_gnapply1(float* __restrict__ xd, const float* __restrict__ mrs,
                                                  const float* __restrict__ g1, const float* __restrict__ b1) {
  int i4 = blockIdx.x * 256 + threadIdx.x;  // float4 index, 2^20 total
  int b = i4 >> 18;
  int c = (i4 >> 12) & 63;
  int g = c >> 1;
  float mu = mrs[b * 32 + g], rs = mrs[128 + b * 32 + g];
  float ga = g1[c] * rs, be = b1[c] - mu * ga;
  float4 v = ((const float4*)xd)[i4];
  v.x = fmaxf(v.x * ga + be, 0.f);
  v.y = fmaxf(v.y * ga + be, 0.f);
  v.z = fmaxf(v.z * ga + be, 0.f);
  v.w = fmaxf(v.w * ga + be, 0.f);
  ((float4*)xd)[i4] = v;
}

// ---- K4: conv3x3 64->18 (offsets), pad 1. grid (256, 2): 9 outs per block ----
__global__ __launch_bounds__(256) void k_off(const float* __restrict__ xd, const float* __restrict__ woff,
                                             float* __restrict__ offs) {
  int tid = threadIdx.x;
  int b = blockIdx.x >> 6;
  int r0 = (blockIdx.x & 63) << 1;
  int o0 = blockIdx.y * 9;
  int y = r0 + (tid >> 7);
  int xc = tid & 127;
  const float* xb = xd + (size_t)b * 64 * HW;
  float acc[9];
#pragma unroll
  for (int o = 0; o < 9; o++) acc[o] = 0.f;
  for (int c = 0; c < 64; c++) {
    const float* pc = xb + (size_t)c * HW;
    float v[3][3];
#pragma unroll
    for (int ky = 0; ky < 3; ky++) {
      int yy = y + ky - 1;
      bool vy = (unsigned)yy < 128u;
#pragma unroll
      for (int kx = 0; kx < 3; kx++) {
        int xx = xc + kx - 1;
        bool vx = (unsigned)xx < 128u;
        v[ky][kx] = (vy && vx) ? pc[yy * WIDTH + xx] : 0.f;
      }
    }
    const float* wc = woff + (size_t)(o0 * 64 + c) * 9;  // w_off [18][64][3][3]
#pragma unroll
    for (int o = 0; o < 9; o++) {
      const float* wo = wc + o * 576;  // uniform -> s_load
#pragma unroll
      for (int k = 0; k < 9; k++) acc[o] += v[k / 3][k % 3] * wo[k];
    }
  }
  float* op = offs + (size_t)b * 18 * HW + (size_t)o0 * HW + y * WIDTH + xc;
#pragma unroll
  for (int o = 0; o < 9; o++) op[(size_t)o * HW] = acc[o];
}

// ---- K5: deform conv, 3-way tap split (blockIdx.y = tap group). part[kg] = partial sums ----
__global__ __launch_bounds__(256) void k_deform3(const float* __restrict__ xd, const float* __restrict__ offs,
                                                 const float* __restrict__ wdT, float* __restrict__ part) {
  int tid = threadIdx.x;
  int b = blockIdx.x >> 6;
  int pix = ((blockIdx.x & 63) << 8) + tid;
  int kg = blockIdx.y;  // 0..2, taps k = 3*kg + {0,1,2}; ky = kg-1
  int y = pix >> 7, xc = pix & 127;
  const float* ob = offs + (size_t)b * 18 * HW + pix;
  const float* xb = xd + (size_t)b * 64 * HW;
  // precompute per-tap bilinear geometry (outside c loop)
  float w00[3], w01[3], w10[3], w11[3];
  int a00[3], a01[3], a10[3], a11[3];
#pragma unroll
  for (int j = 0; j < 3; j++) {
    int k = kg * 3 + j;
    float dy = ob[(size_t)(2 * k) * HW];
    float dx = ob[(size_t)(2 * k + 1) * HW];
    float py = (float)(y + kg - 1) + dy;
    float px = (float)(xc + j - 1) + dx;
    float y0f = floorf(py), x0f = floorf(px);
    float ay = py - y0f, ax = px - x0f;
    int y0 = (int)y0f, x0 = (int)x0f;
    int y1i = y0 + 1, x1i = x0 + 1;
    float by0 = 1.f - ay, bx0 = 1.f - ax;
    bool vy0 = (unsigned)y0 < 128u, vy1 = (unsigned)y1i < 128u;
    bool vx0 = (unsigned)x0 < 128u, vx1 = (unsigned)x1i < 128u;
    w00[j] = (vy0 && vx0) ? by0 * bx0 : 0.f;
    w01[j] = (vy0 && vx1) ? by0 * ax : 0.f;
    w10[j] = (vy1 && vx0) ? ay * bx0 : 0.f;
    w11[j] = (vy1 && vx1) ? ay * ax : 0.f;
    int iy0 = min(max(y0, 0), 127), iy1 = min(max(y1i, 0), 127);
    int ix0 = min(max(x0, 0), 127), ix1 = min(max(x1i, 0), 127);
    a00[j] = iy0 * WIDTH + ix0; a01[j] = iy0 * WIDTH + ix1;
    a10[j] = iy1 * WIDTH + ix0; a11[j] = iy1 * WIDTH + ix1;
  }
  float acc[64];
#pragma unroll
  for (int o = 0; o < 64; o++) acc[o] = 0.f;
#pragma unroll 1
  for (int c = 0; c < 64; c++) {
    const float* pc = xb + (size_t)c * HW;
    float s0 = w00[0] * pc[a00[0]] + w01[0] * pc[a01[0]] + w10[0] * pc[a10[0]] + w11[0] * pc[a11[0]];
    float s1 = w00[1] * pc[a00[1]] + w01[1] * pc[a01[1]] + w10[1] * pc[a10[1]] + w11[1] * pc[a11[1]];
    float s2 = w00[2] * pc[a00[2]] + w01[2] * pc[a01[2]] + w10[2] * pc[a10[2]] + w11[2] * pc[a11[2]];
    const float* wp0 = wdT + (size_t)((kg * 3 + 0) * 64 + c) * 64;  // uniform -> s_load
    const float* wp1 = wdT + (size_t)((kg * 3 + 1) * 64 + c) * 64;
    const float* wp2 = wdT + (size_t)((kg * 3 + 2) * 64 + c) * 64;
#pragma unroll
    for (int o = 0; o < 64; o++) acc[o] += s0 * wp0[o] + s1 * wp1[o] + s2 * wp2[o];
  }
  float* op = part + (size_t)kg * 4194304 + (size_t)b * 64 * HW + pix;
#pragma unroll
  for (int o = 0; o < 64; o++) op[(size_t)o * HW] = acc[o];
}

// ---- K5b: osum = p0 + p1 + p2 + xd (residual) ----
__global__ __launch_bounds__(256) void k_dreduce(const float* __restrict__ part, const float* __restrict__ xd,
                                                 float* __restrict__ osum) {
  int i4 = blockIdx.x * 256 + threadIdx.x;  // 1,048,576 float4
  const float4* p0 = (const float4*)part;
  const float4* p1 = (const float4*)(part + 4194304);
  const float4* p2 = (const float4*)(part + 8388608);
  const float4* xp = (const float4*)xd;
  float4 a = p0[i4], b = p1[i4], c = p2[i4], d = xp[i4];
  float4 r;
  r.x = a.x + b.x + c.x + d.x;
  r.y = a.y + b.y + c.y + d.y;
  r.z = a.z + b.z + c.z + d.z;
  r.w = a.w + b.w + c.w + d.w;
  ((float4*)osum)[i4] = r;
}

// ---- K6: conv1x1 64->256 into t3; grid.y = 4 output-channel chunks of 64 ----
__global__ __launch_bounds__(256) void k_conv2(const float* __restrict__ osum, const float* __restrict__ w3T,
                                               float* __restrict__ t3) {
  int tid = threadIdx.x;
  int lane = tid & 63;
  int o0 = (blockIdx.y << 6) + __builtin_amdgcn_readfirstlane(tid >> 6) * 16;
  int b = blockIdx.x >> 6;
  int hw = ((blockIdx.x & 63) << 8) + (lane << 2);
  const float* ib = osum + (size_t)b * 64 * HW + hw;
  float acc[16][4];
#pragma unroll
  for (int i = 0; i < 16; i++)
#pragma unroll
    for (int j = 0; j < 4; j++) acc[i][j] = 0.f;
  for (int c = 0; c < 64; c++) {
    float4 xv = *(const float4*)(ib + (size_t)c * HW);
    const float* wp = w3T + c * 256 + o0;  // wave-uniform -> s_load
#pragma unroll
    for (int i = 0; i < 16; i++) {
      float w = wp[i];
      acc[i][0] += xv.x * w; acc[i][1] += xv.y * w;
      acc[i][2] += xv.z * w; acc[i][3] += xv.w * w;
    }
  }
  float* tb = t3 + (size_t)b * 256 * HW + hw;
#pragma unroll
  for (int i = 0; i < 16; i++)
    *(float4*)(tb + (size_t)(o0 + i) * HW) = make_float4(acc[i][0], acc[i][1], acc[i][2], acc[i][3]);
}

// ---- K8: out = relu(gn2(t3)) + x ----
__global__ __launch_bounds__(256) void k_final(const float* __restrict__ t3, const float* __restrict__ x,
                                               const float* __restrict__ mrs, const float* __restrict__ g3,
                                               const float* __restrict__ b3, float* __restrict__ out) {
  int i4 = blockIdx.x * 256 + threadIdx.x;  // float4 index, 2^22 total
  int b = i4 >> 20;
  int c = (i4 >> 12) & 255;
  int g = c >> 3;
  float mu = mrs[b * 32 + g], rs = mrs[128 + b * 32 + g];
  float ga = g3[c] * rs, be = b3[c] - mu * ga;
  float4 t = ((const float4*)t3)[i4];
  float4 xv = ((const float4*)x)[i4];
  float4 r;
  r.x = fmaxf(t.x * ga + be, 0.f) + xv.x;
  r.y = fmaxf(t.y * ga + be, 0.f) + xv.y;
  r.z = fmaxf(t.z * ga + be, 0.f) + xv.z;
  r.w = fmaxf(t.w * ga + be, 0.f) + xv.w;
  ((float4*)out)[i4] = r;
}

extern "C" void kernel_launch(void* const* d_in, const int* in_sizes, int n_in,
                              void* d_out, int out_size, void* d_ws, size_t ws_size,
                              hipStream_t stream) {
  const float* x    = (const float*)d_in[0];
  const float* w1   = (const float*)d_in[1];
  const float* g1   = (const float*)d_in[2];
  const float* b1   = (const float*)d_in[3];
  const float* woff = (const float*)d_in[4];
  const float* wdef = (const float*)d_in[5];
  const float* w3   = (const float*)d_in[6];
  const float* g3   = (const float*)d_in[7];
  const float* b3   = (const float*)d_in[8];
  float* ws = (float*)d_ws;

  float* xd   = ws;                 // 4,194,304
  float* offs = xd + 4194304;       // 1,179,648
  float* osum = offs + 1179648;     // 4,194,304
  float* t3   = osum + 4194304;     // 16,777,216 (first 12.58M doubles as deform partials)
  float* mrs1 = t3 + 16777216;      // 256
  float* mrs2 = mrs1 + 256;         // 256
  float* w1T  = mrs2 + 256;         // 16,384
  float* w3T  = w1T + 16384;        // 16,384
  float* wdT  = w3T + 16384;        // 36,864
  float* ps   = wdT + 36864;        // 2,048
  float* out  = (float*)d_out;

  hipLaunchKernelGGL(k_prep, dim3(144), dim3(256), 0, stream, w1, w3, wdef, w1T, w3T, wdT);
  hipLaunchKernelGGL(k_conv1, dim3(256), dim3(512), 0, stream, x, w1T, xd);
  hipLaunchKernelGGL((k_gnstats_part<2, 4>), dim3(128, 4), dim3(256), 0, stream, xd, ps);
  hipLaunchKernelGGL(k_gnfin, dim3(1), dim3(128), 0, stream, ps, mrs1, 4, (float)(2 * HW));
  hipLaunchKernelGGL(k_gnapply1, dim3(4096), dim3(256), 0, stream, xd, mrs1, g1, b1);
  hipLaunchKernelGGL(k_off, dim3(256, 2), dim3(256), 0, stream, xd, woff, offs);
  hipLaunchKernelGGL(k_deform3, dim3(256, 3), dim3(256), 0, stream, xd, offs, wdT, t3);
  hipLaunchKernelGGL(k_dreduce, dim3(4096), dim3(256), 0, stream, t3, xd, osum);
  hipLaunchKernelGGL(k_conv2, dim3(256, 4), dim3(256), 0, stream, osum, w3T, t3);
  hipLaunchKernelGGL((k_gnstats_part<8, 8>), dim3(128, 8), dim3(256), 0, stream, t3, ps);
  hipLaunchKernelGGL(k_gnfin, dim3(1), dim3(128), 0, stream, ps, mrs2, 8, (float)(8 * HW));
  hipLaunchKernelGGL(k_final, dim3(16384), dim3(256), 0, stream, t3, x, mrs2, g3, b3, out);
}